// Round 2
// baseline (580.734 us; speedup 1.0000x reference)
//
#include <hip/hip_runtime.h>

// DINOMIMICClassification: per-sample 3-layer expert MLP (E=16,B=512,D=1536,H=768,T=2).
// Expert-grouped GEMM. Memory-bound on streaming W1 (75.5MB) + W2 (37.7MB) once.
// R1: KSPLIT 4->8 (1536 blocks), double-buffered LDS staging with global_load_lds
// for W so next-stage loads are in flight while current stage computes.

namespace {
constexpr int NE = 16, NB = 512, ND = 1536, NH = 768;
constexpr int CT = 64;          // columns per block tile
constexpr int KT = 32;          // k rows per LDS stage
constexpr int NCT = NH / CT;    // 12 column tiles
constexpr int KS = 8;           // k-splits per layer

__device__ __forceinline__ void gload_lds16(const float* g, float* l) {
    __builtin_amdgcn_global_load_lds(
        (const __attribute__((address_space(1))) void*)g,
        (__attribute__((address_space(3))) void*)l, 16, 0, 0);
}

// part[ks][b][c0..c0+63] += sum_{k in split ks} act[b][k] * W[e_b][k][c]
template<int DIN>
__global__ __launch_bounds__(256, 4)
void grouped_mm(const float* __restrict__ act,   // [NB][DIN]
                const int*   __restrict__ head_idx,
                const float* __restrict__ W,     // [NE][DIN][NH]
                float*       __restrict__ part)  // [KS][NB][NH]
{
    constexpr int KLEN = DIN / KS;
    constexpr int NST  = KLEN / KT;   // stages
    const int bid = blockIdx.x;
    const int e   = bid / (NCT * KS);
    const int rem = bid % (NCT * KS);
    const int j   = rem / KS;
    const int ks  = rem % KS;
    const int tid = threadIdx.x;

    __shared__ int lst[NB];
    __shared__ int n_sh;
    if (tid < 64) {   // wave 0: ballot-compact this expert's sample list
        int cnt = 0;
        for (int base = 0; base < NB; base += 64) {
            const int h = head_idx[base + tid];
            const unsigned long long m = __ballot(h == e);
            const int pos = cnt + __popcll(m & ((1ull << tid) - 1ull));
            if (h == e) lst[pos] = base + tid;
            cnt += __popcll(m);
        }
        if (tid == 0) n_sh = cnt;
    }
    __syncthreads();
    const int n = n_sh;
    if (n == 0) return;

    const int c0 = j * CT;
    const int k0 = ks * KLEN;
    const float* Wp   = W + ((size_t)e * DIN) * NH;
    float*       outp = part + ((size_t)ks * NB) * NH;

    __shared__ float Ws[2][KT][CT];   // [k][c] double-buffered (8KB each)
    __shared__ float Xs[2][KT][64];   // [k][s] double-buffered (8KB each)

    const int cg = tid & 15;   // col group (4 cols)
    const int sg = tid >> 4;   // sample group (4 samples)

    // staging thread mapping (fixed):
    const int w_kk = tid >> 4;          // W: rows w_kk, w_kk+16
    const int w_cc = (tid & 15) * 4;    //    cols w_cc..+3 (lane-linear LDS dest)
    const int x_s  = tid & 63;          // X: sample slot
    const int x_kq = tid >> 6;          //    k = x_kq*8 .. +7

    for (int s0 = 0; s0 < n; s0 += 64) {
        float acc[4][4];
        #pragma unroll
        for (int i = 0; i < 4; ++i)
            #pragma unroll
            for (int q = 0; q < 4; ++q) acc[i][q] = 0.f;

        // ---- stage helpers (inline) ----
        auto stageW = [&](int buf, int kt) {
            const float* g = Wp + (size_t)(k0 + kt + w_kk) * NH + c0 + w_cc;
            gload_lds16(g,                     &Ws[buf][w_kk][w_cc]);
            gload_lds16(g + (size_t)16 * NH,   &Ws[buf][w_kk + 16][w_cc]);
        };
        auto stageX = [&](int buf, int kt) {
            if (s0 + x_s < n) {
                const float* g = act + (size_t)lst[s0 + x_s] * DIN + k0 + kt + x_kq * 8;
                const float4 v0 = *(const float4*)g;
                const float4 v1 = *(const float4*)(g + 4);
                Xs[buf][x_kq*8+0][x_s] = v0.x; Xs[buf][x_kq*8+1][x_s] = v0.y;
                Xs[buf][x_kq*8+2][x_s] = v0.z; Xs[buf][x_kq*8+3][x_s] = v0.w;
                Xs[buf][x_kq*8+4][x_s] = v1.x; Xs[buf][x_kq*8+5][x_s] = v1.y;
                Xs[buf][x_kq*8+6][x_s] = v1.z; Xs[buf][x_kq*8+7][x_s] = v1.w;
            } else {
                #pragma unroll
                for (int i = 0; i < 8; ++i) Xs[buf][x_kq*8+i][x_s] = 0.f;
            }
        };

        // prologue: fill buffer 0
        stageW(0, 0);
        stageX(0, 0);
        __syncthreads();

        for (int t = 0; t < NST; ++t) {
            const int cur = t & 1;
            if (t + 1 < NST) {               // issue next stage while computing
                stageW(cur ^ 1, (t + 1) * KT);
                stageX(cur ^ 1, (t + 1) * KT);
            }
            #pragma unroll
            for (int k = 0; k < KT; ++k) {
                const float4 wv = *(const float4*)&Ws[cur][k][cg * 4];
                const float4 xv = *(const float4*)&Xs[cur][k][sg * 4];
                acc[0][0] += xv.x*wv.x; acc[0][1] += xv.x*wv.y; acc[0][2] += xv.x*wv.z; acc[0][3] += xv.x*wv.w;
                acc[1][0] += xv.y*wv.x; acc[1][1] += xv.y*wv.y; acc[1][2] += xv.y*wv.z; acc[1][3] += xv.y*wv.w;
                acc[2][0] += xv.z*wv.x; acc[2][1] += xv.z*wv.y; acc[2][2] += xv.z*wv.z; acc[2][3] += xv.z*wv.w;
                acc[3][0] += xv.w*wv.x; acc[3][1] += xv.w*wv.y; acc[3][2] += xv.w*wv.z; acc[3][3] += xv.w*wv.w;
            }
            __syncthreads();   // waits own vmcnt/lgkm (incl. next-stage loads) + barrier
        }

        #pragma unroll
        for (int si = 0; si < 4; ++si) {
            const int s = s0 + sg * 4 + si;
            if (s < n) {
                float* o = outp + (size_t)lst[s] * NH + c0 + cg * 4;
                *(float4*)o = make_float4(acc[si][0], acc[si][1], acc[si][2], acc[si][3]);
            }
        }
    }
}

// h1[b][c] = relu(b1[e_b][c] + sum_ks part[ks][b][c])
__global__ __launch_bounds__(256)
void combine_relu(const float* __restrict__ part,   // [KS][NB][NH]
                  const float* __restrict__ bias,   // [NE][NH]
                  const int*   __restrict__ head_idx,
                  float*       __restrict__ outp)   // [NB][NH]
{
    const int i = blockIdx.x * 256 + threadIdx.x;    // float4 index
    if (i >= NB * NH / 4) return;
    const int b  = i / (NH / 4);
    const int c4 = i % (NH / 4);
    constexpr int STR = NB * NH / 4;
    const float4* P = (const float4*)part;
    const int e = head_idx[b];
    const float4 bb = ((const float4*)bias)[e * (NH / 4) + c4];
    float sx = bb.x, sy = bb.y, sz = bb.z, sw = bb.w;
    #pragma unroll
    for (int ks = 0; ks < KS; ++ks) {
        const float4 v = P[i + ks * STR];
        sx += v.x; sy += v.y; sz += v.z; sw += v.w;
    }
    float4 o;
    o.x = fmaxf(sx, 0.f); o.y = fmaxf(sy, 0.f);
    o.z = fmaxf(sz, 0.f); o.w = fmaxf(sw, 0.f);
    ((float4*)outp)[i] = o;
}

// out[b][t] = relu(sum_ks h2p[ks][b][:] + b2[e]) . W3[e][:,t] + b3[e][t]
// one wave per sample; 4 samples per block
__global__ __launch_bounds__(256)
void final_head(const float* __restrict__ h2p,  // [KS][NB][NH]
                const float* __restrict__ b2,   // [NE][NH]
                const float* __restrict__ W3,   // [NE][NH][2]
                const float* __restrict__ b3,   // [NE][2]
                const int*   __restrict__ head_idx,
                float*       __restrict__ out)  // [NB][2]
{
    const int b    = blockIdx.x * 4 + (threadIdx.x >> 6);
    const int lane = threadIdx.x & 63;
    const int e    = head_idx[b];
    constexpr size_t STR = (size_t)NB * NH;
    float a0 = 0.f, a1 = 0.f;
    for (int h = lane; h < NH; h += 64) {
        const size_t o = (size_t)b * NH + h;
        float s = b2[e * NH + h];
        #pragma unroll
        for (int ks = 0; ks < KS; ++ks) s += h2p[ks * STR + o];
        s = fmaxf(s, 0.f);
        const float2 w = *(const float2*)&W3[((size_t)e * NH + h) * 2];
        a0 += s * w.x;
        a1 += s * w.y;
    }
    #pragma unroll
    for (int off = 32; off > 0; off >>= 1) {
        a0 += __shfl_down(a0, off);
        a1 += __shfl_down(a1, off);
    }
    if (lane == 0) {
        out[b * 2 + 0] = a0 + b3[e * 2 + 0];
        out[b * 2 + 1] = a1 + b3[e * 2 + 1];
    }
}
} // namespace

extern "C" void kernel_launch(void* const* d_in, const int* in_sizes, int n_in,
                              void* d_out, int out_size, void* d_ws, size_t ws_size,
                              hipStream_t stream) {
    const float* x   = (const float*)d_in[0];
    const int*   hi  = (const int*)  d_in[1];
    const float* W1  = (const float*)d_in[2];
    const float* b1  = (const float*)d_in[3];
    const float* W2  = (const float*)d_in[4];
    const float* b2  = (const float*)d_in[5];
    const float* W3  = (const float*)d_in[6];
    const float* b3  = (const float*)d_in[7];
    float* out = (float*)d_out;

    // ws layout (fp32): part [KS][B][H] (12.6MB, reused for h2p) | h1 [B][H] (1.5MB)
    float* h1p = (float*)d_ws;
    float* h1  = h1p + (size_t)KS * NB * NH;
    float* h2p = h1p;   // alias: h1p dead after combine_relu

    grouped_mm<ND><<<NE * NCT * KS, 256, 0, stream>>>(x,  hi, W1, h1p);
    combine_relu<<<(NB * NH / 4 + 255) / 256, 256, 0, stream>>>(h1p, b1, hi, h1);
    grouped_mm<NH><<<NE * NCT * KS, 256, 0, stream>>>(h1, hi, W2, h2p);
    final_head<<<NB / 4, 256, 0, stream>>>(h2p, b2, W3, b3, hi, out);
}

// Round 3
// 219.321 us; speedup vs baseline: 2.6479x; 2.6479x over previous
//
#include <hip/hip_runtime.h>

// DINOMIMICClassification: per-sample 3-layer expert MLP (E=16,B=512,D=1536,H=768,T=2).
// R2 postmortem: global_load_lds with per-lane-divergent LDS ptr => waterfall +
// 4x line overfetch (FETCH 384MB, 270us). R3: no W LDS at all — stream W
// global->VGPR (L1 absorbs the 4x sg-group redundancy), X transposed in LDS
// staged once, zero barriers in the k-loop, SB=32 sample tiles (n~32/expert).

namespace {
constexpr int NE = 16, NB = 512, ND = 1536, NH = 768;
constexpr int CT  = 64;        // cols per block tile
constexpr int SB  = 32;        // samples per block tile
constexpr int KS1 = 16;        // k-splits layer 1 (KLEN = 96)
constexpr int KS2 = 8;         // k-splits layer 2 (KLEN = 96)
constexpr int NCT = NH / CT;   // 12

// part[ks][b][c0..c0+63] = sum_{k in split ks} act[b][k] * W[e_b][k][c]
template<int DIN, int KSN>
__global__ __launch_bounds__(128, 4)
void grouped_mm(const float* __restrict__ act,   // [NB][DIN]
                const int*   __restrict__ head_idx,
                const float* __restrict__ W,     // [NE][DIN][NH]
                float*       __restrict__ part)  // [KSN][NB][NH]
{
    constexpr int KLEN = DIN / KSN;   // 96
    const int bid = blockIdx.x;
    const int e   = bid / (NCT * KSN);
    const int rem = bid % (NCT * KSN);
    const int j   = rem / KSN;
    const int ks  = rem % KSN;
    const int tid = threadIdx.x;

    __shared__ int lst[NB];
    __shared__ int n_sh;
    if (tid < 64) {   // wave 0: ballot-compact this expert's sample list
        int cnt = 0;
        for (int base = 0; base < NB; base += 64) {
            const int h = head_idx[base + tid];
            const unsigned long long m = __ballot(h == e);
            const int pos = cnt + __popcll(m & ((1ull << tid) - 1ull));
            if (h == e) lst[pos] = base + tid;
            cnt += __popcll(m);
        }
        if (tid == 0) n_sh = cnt;
    }
    __syncthreads();
    const int n = n_sh;
    if (n == 0) return;

    const int c0 = j * CT;
    const int k0 = ks * KLEN;
    const int cg = tid & 15;          // 4-col group
    const int sg = tid >> 4;          // 4-sample group (0..7)
    const float* Wk = W + ((size_t)e * DIN + k0) * NH + c0 + cg * 4;
    float* outp = part + ((size_t)ks * NB) * NH;

    __shared__ float Xs[KLEN][SB];    // [k][s] transposed activations (12KB)

    const int x_s  = tid & 31;        // sample slot
    const int x_kq = tid >> 5;        // k quarter (0..3)
    constexpr int KF = KLEN / 4;      // floats per staging thread (24)

    for (int s0 = 0; s0 < n; s0 += SB) {
        __syncthreads();   // protect Xs from previous iteration's readers
        if (s0 + x_s < n) {
            const float* g = act + (size_t)lst[s0 + x_s] * DIN + k0 + x_kq * KF;
            #pragma unroll
            for (int i = 0; i < KF / 4; ++i) {
                const float4 v = *(const float4*)(g + i * 4);
                Xs[x_kq*KF + i*4 + 0][x_s] = v.x;
                Xs[x_kq*KF + i*4 + 1][x_s] = v.y;
                Xs[x_kq*KF + i*4 + 2][x_s] = v.z;
                Xs[x_kq*KF + i*4 + 3][x_s] = v.w;
            }
        } else {
            #pragma unroll
            for (int i = 0; i < KF; ++i) Xs[x_kq*KF + i][x_s] = 0.f;
        }
        __syncthreads();

        float acc[4][4];
        #pragma unroll
        for (int i = 0; i < 4; ++i)
            #pragma unroll
            for (int q = 0; q < 4; ++q) acc[i][q] = 0.f;

        // k-loop: W streamed global->reg (8 loads in flight), X from LDS broadcast.
        // No barriers, no W LDS.
        #pragma unroll 1
        for (int kb = 0; kb < KLEN; kb += 8) {
            float4 wv[8];
            #pragma unroll
            for (int u = 0; u < 8; ++u)
                wv[u] = *(const float4*)(Wk + (size_t)(kb + u) * NH);
            #pragma unroll
            for (int u = 0; u < 8; ++u) {
                const float4 xv = *(const float4*)&Xs[kb + u][sg * 4];
                acc[0][0] += xv.x*wv[u].x; acc[0][1] += xv.x*wv[u].y; acc[0][2] += xv.x*wv[u].z; acc[0][3] += xv.x*wv[u].w;
                acc[1][0] += xv.y*wv[u].x; acc[1][1] += xv.y*wv[u].y; acc[1][2] += xv.y*wv[u].z; acc[1][3] += xv.y*wv[u].w;
                acc[2][0] += xv.z*wv[u].x; acc[2][1] += xv.z*wv[u].y; acc[2][2] += xv.z*wv[u].z; acc[2][3] += xv.z*wv[u].w;
                acc[3][0] += xv.w*wv[u].x; acc[3][1] += xv.w*wv[u].y; acc[3][2] += xv.w*wv[u].z; acc[3][3] += xv.w*wv[u].w;
            }
        }

        #pragma unroll
        for (int si = 0; si < 4; ++si) {
            const int s = s0 + sg * 4 + si;
            if (s < n) {
                float* o = outp + (size_t)lst[s] * NH + c0 + cg * 4;
                *(float4*)o = make_float4(acc[si][0], acc[si][1], acc[si][2], acc[si][3]);
            }
        }
    }
}

// h1[b][c] = relu(b1[e_b][c] + sum_ks part[ks][b][c])
template<int KSN>
__global__ __launch_bounds__(256)
void combine_relu(const float* __restrict__ part,   // [KSN][NB][NH]
                  const float* __restrict__ bias,   // [NE][NH]
                  const int*   __restrict__ head_idx,
                  float*       __restrict__ outp)   // [NB][NH]
{
    const int i = blockIdx.x * 256 + threadIdx.x;    // float4 index
    if (i >= NB * NH / 4) return;
    const int b  = i / (NH / 4);
    const int c4 = i % (NH / 4);
    constexpr int STR = NB * NH / 4;
    const float4* P = (const float4*)part;
    const int e = head_idx[b];
    const float4 bb = ((const float4*)bias)[e * (NH / 4) + c4];
    float sx = bb.x, sy = bb.y, sz = bb.z, sw = bb.w;
    #pragma unroll
    for (int ks = 0; ks < KSN; ++ks) {
        const float4 v = P[i + ks * STR];
        sx += v.x; sy += v.y; sz += v.z; sw += v.w;
    }
    float4 o;
    o.x = fmaxf(sx, 0.f); o.y = fmaxf(sy, 0.f);
    o.z = fmaxf(sz, 0.f); o.w = fmaxf(sw, 0.f);
    ((float4*)outp)[i] = o;
}

// out[b][t] = relu(sum_ks h2p[ks][b][:] + b2[e]) . W3[e][:,t] + b3[e][t]
template<int KSN>
__global__ __launch_bounds__(256)
void final_head(const float* __restrict__ h2p,  // [KSN][NB][NH]
                const float* __restrict__ b2,   // [NE][NH]
                const float* __restrict__ W3,   // [NE][NH][2]
                const float* __restrict__ b3,   // [NE][2]
                const int*   __restrict__ head_idx,
                float*       __restrict__ out)  // [NB][2]
{
    const int b    = blockIdx.x * 4 + (threadIdx.x >> 6);
    const int lane = threadIdx.x & 63;
    const int e    = head_idx[b];
    constexpr size_t STR = (size_t)NB * NH;
    float a0 = 0.f, a1 = 0.f;
    for (int h = lane; h < NH; h += 64) {
        const size_t o = (size_t)b * NH + h;
        float s = b2[e * NH + h];
        #pragma unroll
        for (int ks = 0; ks < KSN; ++ks) s += h2p[ks * STR + o];
        s = fmaxf(s, 0.f);
        const float2 w = *(const float2*)&W3[((size_t)e * NH + h) * 2];
        a0 += s * w.x;
        a1 += s * w.y;
    }
    #pragma unroll
    for (int off = 32; off > 0; off >>= 1) {
        a0 += __shfl_down(a0, off);
        a1 += __shfl_down(a1, off);
    }
    if (lane == 0) {
        out[b * 2 + 0] = a0 + b3[e * 2 + 0];
        out[b * 2 + 1] = a1 + b3[e * 2 + 1];
    }
}
} // namespace

extern "C" void kernel_launch(void* const* d_in, const int* in_sizes, int n_in,
                              void* d_out, int out_size, void* d_ws, size_t ws_size,
                              hipStream_t stream) {
    const float* x   = (const float*)d_in[0];
    const int*   hi  = (const int*)  d_in[1];
    const float* W1  = (const float*)d_in[2];
    const float* b1  = (const float*)d_in[3];
    const float* W2  = (const float*)d_in[4];
    const float* b2  = (const float*)d_in[5];
    const float* W3  = (const float*)d_in[6];
    const float* b3  = (const float*)d_in[7];
    float* out = (float*)d_out;

    // ws (fp32): h1p [KS1][B][H] 25.2MB (reused as h2p [KS2][B][H]) | h1 [B][H] 1.5MB
    float* h1p = (float*)d_ws;
    float* h1  = h1p + (size_t)KS1 * NB * NH;
    float* h2p = h1p;   // alias: h1p dead after combine_relu

    grouped_mm<ND, KS1><<<NE * NCT * KS1, 128, 0, stream>>>(x,  hi, W1, h1p);
    combine_relu<KS1><<<(NB * NH / 4 + 255) / 256, 256, 0, stream>>>(h1p, b1, hi, h1);
    grouped_mm<NH, KS2><<<NE * NCT * KS2, 128, 0, stream>>>(h1, hi, W2, h2p);
    final_head<KS2><<<NB / 4, 256, 0, stream>>>(h2p, b2, W3, b3, hi, out);
}